// Round 1
// baseline (2412.695 us; speedup 1.0000x reference)
//
#include <hip/hip_runtime.h>
#include <stdint.h>

#define D_DIM 512
#define H_DIM 2048
#define E_NUM 8
#define TOPK_N 2

#define BM 64
#define BN 64
#define BK 64
#define LDP 72   // 64 + 8 pad: 144B row stride, 16B aligned, 2-way bank alias (free)

typedef __attribute__((ext_vector_type(8))) short bf16x8;
typedef __attribute__((ext_vector_type(4))) float f32x4;

static __device__ __forceinline__ unsigned short f2bf(float f) {
    unsigned u = __float_as_uint(f);
    unsigned r = (u + 0x7fffu + ((u >> 16) & 1u)) >> 16;
    return (unsigned short)r;
}

// ---------------- init: list=-1, counts=0 ----------------
__global__ void init_kernel(int* counts, int* list_token, float* list_w, int cap) {
    int id = blockIdx.x * blockDim.x + threadIdx.x;
    if (id < cap) { list_token[id] = -1; list_w[id] = 0.f; }
    if (id < E_NUM) counts[id] = 0;
}

// ---------------- x fp32 -> bf16 ----------------
__global__ void cvt_x_kernel(const float* __restrict__ x, unsigned short* __restrict__ xb, int n8) {
    int id = blockIdx.x * blockDim.x + threadIdx.x;
    if (id >= n8) return;
    const float4* p = (const float4*)(x + (size_t)id * 8);
    float4 a = p[0], b = p[1];
    union { unsigned short s[8]; uint4 v; } o;
    o.s[0] = f2bf(a.x); o.s[1] = f2bf(a.y); o.s[2] = f2bf(a.z); o.s[3] = f2bf(a.w);
    o.s[4] = f2bf(b.x); o.s[5] = f2bf(b.y); o.s[6] = f2bf(b.z); o.s[7] = f2bf(b.w);
    *(uint4*)(xb + (size_t)id * 8) = o.v;
}

// ------------- transpose+convert: in fp32 [E][R][C] -> out bf16 [E][C][R] -------------
__global__ void tconv_kernel(const float* __restrict__ in, unsigned short* __restrict__ out,
                             int R, int C) {
    __shared__ float tile[32][33];
    int e = blockIdx.z;
    const float* src = in + (size_t)e * R * C;
    unsigned short* dst = out + (size_t)e * R * C;
    int c = blockIdx.x * 32 + threadIdx.x;
#pragma unroll
    for (int i = 0; i < 4; ++i) {
        int r = blockIdx.y * 32 + threadIdx.y + i * 8;
        tile[threadIdx.y + i * 8][threadIdx.x] = src[(size_t)r * C + c];
    }
    __syncthreads();
    int r2 = blockIdx.y * 32 + threadIdx.x;
#pragma unroll
    for (int i = 0; i < 4; ++i) {
        int c2 = blockIdx.x * 32 + threadIdx.y + i * 8;
        dst[(size_t)c2 * R + r2] = f2bf(tile[threadIdx.x][threadIdx.y + i * 8]);
    }
}

// ---------------- gating: fp32 logits, top-2 softmax ----------------
__global__ void gate_kernel(const float* __restrict__ x, const float* __restrict__ gw,
                            int* __restrict__ ridx, float* __restrict__ rw,
                            int* __restrict__ counts, int T) {
    int wave = threadIdx.x >> 6;
    int lane = threadIdx.x & 63;
    int t = blockIdx.x * 4 + wave;
    if (t >= T) return;
    float acc[8] = {0.f, 0.f, 0.f, 0.f, 0.f, 0.f, 0.f, 0.f};
    const float* xr = x + (size_t)t * D_DIM;
#pragma unroll
    for (int i = 0; i < 8; ++i) {
        int d = lane + i * 64;
        float xv = xr[d];
        float4 g0 = *(const float4*)(gw + d * 8);
        float4 g1 = *(const float4*)(gw + d * 8 + 4);
        acc[0] += xv * g0.x; acc[1] += xv * g0.y; acc[2] += xv * g0.z; acc[3] += xv * g0.w;
        acc[4] += xv * g1.x; acc[5] += xv * g1.y; acc[6] += xv * g1.z; acc[7] += xv * g1.w;
    }
#pragma unroll
    for (int off = 32; off > 0; off >>= 1) {
#pragma unroll
        for (int e = 0; e < 8; ++e) acc[e] += __shfl_xor(acc[e], off, 64);
    }
    if (lane == 0) {
        int e0 = 0; float l0 = acc[0];
#pragma unroll
        for (int e = 1; e < 8; ++e) if (acc[e] > l0) { l0 = acc[e]; e0 = e; }
        int e1 = -1; float l1 = -1e30f;
#pragma unroll
        for (int e = 0; e < 8; ++e) if (e != e0 && acc[e] > l1) { l1 = acc[e]; e1 = e; }
        float w0 = 1.f / (1.f + expf(l1 - l0));
        ridx[t * 2] = e0; ridx[t * 2 + 1] = e1;
        rw[t * 2] = w0;  rw[t * 2 + 1] = 1.f - w0;
        atomicAdd(&counts[e0], 1);
        atomicAdd(&counts[e1], 1);
    }
}

// ---------------- scan: padded segment offsets ----------------
__global__ void scan_kernel(const int* __restrict__ counts, int* __restrict__ seg,
                            int* __restrict__ fill) {
    if (blockIdx.x == 0 && threadIdx.x == 0) {
        int off = 0;
        for (int e = 0; e < E_NUM; ++e) {
            seg[e] = off;
            fill[e] = off;
            off += (counts[e] + 63) & ~63;
        }
        seg[E_NUM] = off;
    }
}

// ---------------- scatter pairs into expert segments ----------------
__global__ void scatter_kernel(const int* __restrict__ ridx, const float* __restrict__ rw,
                               int* __restrict__ fill, int* __restrict__ list_token,
                               float* __restrict__ list_w, int npairs) {
    int id = blockIdx.x * blockDim.x + threadIdx.x;
    if (id >= npairs) return;
    int e = ridx[id];
    int pos = atomicAdd(&fill[e], 1);
    list_token[pos] = id >> 1;
    list_w[pos] = rw[id];
}

// ---------------- GEMM1: h = silu(X W1) * (X W3), gathered rows ----------------
__global__ __launch_bounds__(256) void gemm1_kernel(
    const unsigned short* __restrict__ xb,
    const unsigned short* __restrict__ w1t,   // [E][H][D] bf16 (K-contiguous)
    const unsigned short* __restrict__ w3t,
    const int* __restrict__ list_token,
    const int* __restrict__ seg,
    unsigned short* __restrict__ hbuf,        // [chunk_slots][H] bf16
    int chunk_base) {
    __shared__ short As[BM][LDP];
    __shared__ short B1[BN][LDP];
    __shared__ short B3[BN][LDP];
    __shared__ int tokid[BM];
    __shared__ int expert_s;

    int tid = threadIdx.x;
    int m0 = blockIdx.x * BM;          // local within chunk
    int slot0 = chunk_base + m0;
    int n0 = blockIdx.y * BN;

    if (tid < BM) tokid[tid] = list_token[slot0 + tid];
    if (tid == 0) {
        int e = 0;
        while (e < E_NUM - 1 && slot0 >= seg[e + 1]) ++e;
        expert_s = e;
    }
    __syncthreads();
    int e = expert_s;
    const unsigned short* b1base = w1t + ((size_t)e * H_DIM + n0) * D_DIM;
    const unsigned short* b3base = w3t + ((size_t)e * H_DIM + n0) * D_DIM;

    int wv = tid >> 6;
    int lane = tid & 63;
    int wm = (wv & 1) * 32;
    int wn = (wv >> 1) * 32;
    int lr = lane & 15;
    int lk = (lane >> 4) * 8;

    f32x4 acc1[2][2] = {};
    f32x4 acc3[2][2] = {};

    int tr = tid >> 3;
    int tc = (tid & 7) * 8;

    for (int k0 = 0; k0 < D_DIM; k0 += BK) {
#pragma unroll
        for (int rr0 = 0; rr0 < BM; rr0 += 32) {
            int rr = rr0 + tr;
            int tok = tokid[rr];
            uint4 v = make_uint4(0, 0, 0, 0);
            if (tok >= 0) v = *(const uint4*)(xb + (size_t)tok * D_DIM + k0 + tc);
            *(uint4*)(&As[rr][tc]) = v;
            *(uint4*)(&B1[rr][tc]) = *(const uint4*)(b1base + (size_t)rr * D_DIM + k0 + tc);
            *(uint4*)(&B3[rr][tc]) = *(const uint4*)(b3base + (size_t)rr * D_DIM + k0 + tc);
        }
        __syncthreads();
#pragma unroll
        for (int ks = 0; ks < BK; ks += 32) {
            bf16x8 a[2], b1f[2], b3f[2];
#pragma unroll
            for (int i = 0; i < 2; ++i) a[i] = *(const bf16x8*)(&As[wm + i * 16 + lr][ks + lk]);
#pragma unroll
            for (int j = 0; j < 2; ++j) {
                b1f[j] = *(const bf16x8*)(&B1[wn + j * 16 + lr][ks + lk]);
                b3f[j] = *(const bf16x8*)(&B3[wn + j * 16 + lr][ks + lk]);
            }
#pragma unroll
            for (int i = 0; i < 2; ++i)
#pragma unroll
                for (int j = 0; j < 2; ++j) {
                    acc1[i][j] = __builtin_amdgcn_mfma_f32_16x16x32_bf16(a[i], b1f[j], acc1[i][j], 0, 0, 0);
                    acc3[i][j] = __builtin_amdgcn_mfma_f32_16x16x32_bf16(a[i], b3f[j], acc3[i][j], 0, 0, 0);
                }
        }
        __syncthreads();
    }

    int lrow = (lane >> 4) * 4;
    int lcol = lane & 15;
#pragma unroll
    for (int i = 0; i < 2; ++i)
#pragma unroll
        for (int j = 0; j < 2; ++j)
#pragma unroll
            for (int r = 0; r < 4; ++r) {
                int row = wm + i * 16 + lrow + r;
                int col = wn + j * 16 + lcol;
                float v1 = acc1[i][j][r];
                float v3 = acc3[i][j][r];
                float h = v1 / (1.f + expf(-v1)) * v3;
                hbuf[(size_t)(m0 + row) * H_DIM + n0 + col] = f2bf(h);
            }
}

// ---------------- GEMM2: out[token] += w * (h W2) ----------------
__global__ __launch_bounds__(256) void gemm2_kernel(
    const unsigned short* __restrict__ hbuf,  // [chunk_slots][H]
    const unsigned short* __restrict__ w2t,   // [E][D][H] bf16 (K-contiguous)
    const int* __restrict__ list_token,
    const float* __restrict__ list_w,
    const int* __restrict__ seg,
    float* __restrict__ out,
    int chunk_base) {
    __shared__ short As[BM][LDP];
    __shared__ short B2[BN][LDP];
    __shared__ int tokid[BM];
    __shared__ float wrow[BM];
    __shared__ int expert_s;

    int tid = threadIdx.x;
    int m0 = blockIdx.x * BM;
    int slot0 = chunk_base + m0;
    int n0 = blockIdx.y * BN;

    if (tid < BM) {
        tokid[tid] = list_token[slot0 + tid];
        wrow[tid] = list_w[slot0 + tid];
    }
    if (tid == 0) {
        int e = 0;
        while (e < E_NUM - 1 && slot0 >= seg[e + 1]) ++e;
        expert_s = e;
    }
    __syncthreads();
    int e = expert_s;
    const unsigned short* b2base = w2t + ((size_t)e * D_DIM + n0) * H_DIM;

    int wv = tid >> 6;
    int lane = tid & 63;
    int wm = (wv & 1) * 32;
    int wn = (wv >> 1) * 32;
    int lr = lane & 15;
    int lk = (lane >> 4) * 8;

    f32x4 acc[2][2] = {};

    int tr = tid >> 3;
    int tc = (tid & 7) * 8;

    for (int k0 = 0; k0 < H_DIM; k0 += BK) {
#pragma unroll
        for (int rr0 = 0; rr0 < BM; rr0 += 32) {
            int rr = rr0 + tr;
            *(uint4*)(&As[rr][tc]) = *(const uint4*)(hbuf + (size_t)(m0 + rr) * H_DIM + k0 + tc);
            *(uint4*)(&B2[rr][tc]) = *(const uint4*)(b2base + (size_t)rr * H_DIM + k0 + tc);
        }
        __syncthreads();
#pragma unroll
        for (int ks = 0; ks < BK; ks += 32) {
            bf16x8 a[2], bf[2];
#pragma unroll
            for (int i = 0; i < 2; ++i) a[i] = *(const bf16x8*)(&As[wm + i * 16 + lr][ks + lk]);
#pragma unroll
            for (int j = 0; j < 2; ++j) bf[j] = *(const bf16x8*)(&B2[wn + j * 16 + lr][ks + lk]);
#pragma unroll
            for (int i = 0; i < 2; ++i)
#pragma unroll
                for (int j = 0; j < 2; ++j)
                    acc[i][j] = __builtin_amdgcn_mfma_f32_16x16x32_bf16(a[i], bf[j], acc[i][j], 0, 0, 0);
        }
        __syncthreads();
    }

    int lrow = (lane >> 4) * 4;
    int lcol = lane & 15;
#pragma unroll
    for (int i = 0; i < 2; ++i)
#pragma unroll
        for (int j = 0; j < 2; ++j)
#pragma unroll
            for (int r = 0; r < 4; ++r) {
                int row = wm + i * 16 + lrow + r;
                int col = wn + j * 16 + lcol;
                int tok = tokid[row];
                if (tok >= 0) {
                    atomicAdd(&out[(size_t)tok * D_DIM + n0 + col], acc[i][j][r] * wrow[row]);
                }
            }
}

extern "C" void kernel_launch(void* const* d_in, const int* in_sizes, int n_in,
                              void* d_out, int out_size, void* d_ws, size_t ws_size,
                              hipStream_t stream) {
    const float* x  = (const float*)d_in[0];
    const float* gw = (const float*)d_in[1];
    const float* W1 = (const float*)d_in[2];
    const float* W2 = (const float*)d_in[3];
    const float* W3 = (const float*)d_in[4];
    float* out = (float*)d_out;

    int T = in_sizes[0] / D_DIM;           // 32768
    int npairs = T * TOPK_N;               // 65536
    const int CAP = ((npairs + 63) & ~63) + E_NUM * 64;   // 66048
    const int NCHUNK = 8;
    int chunk_slots = CAP / NCHUNK;        // 8256 = 129 * 64

    char* p = (char*)d_ws;
    size_t off = 0;
    auto take = [&](size_t bytes) {
        char* r = p + off;
        off = (off + bytes + 255) & ~(size_t)255;
        return r;
    };
    int* counts        = (int*)take(E_NUM * 4);
    int* seg           = (int*)take((E_NUM + 1) * 4);
    int* fill          = (int*)take(E_NUM * 4);
    int* list_token    = (int*)take((size_t)CAP * 4);
    float* list_w      = (float*)take((size_t)CAP * 4);
    int* ridx          = (int*)take((size_t)npairs * 4);
    float* rw          = (float*)take((size_t)npairs * 4);
    unsigned short* xb  = (unsigned short*)take((size_t)T * D_DIM * 2);
    unsigned short* w1t = (unsigned short*)take((size_t)E_NUM * D_DIM * H_DIM * 2);
    unsigned short* w3t = (unsigned short*)take((size_t)E_NUM * D_DIM * H_DIM * 2);
    unsigned short* w2t = (unsigned short*)take((size_t)E_NUM * D_DIM * H_DIM * 2);
    unsigned short* hbuf = (unsigned short*)take((size_t)chunk_slots * H_DIM * 2);
    (void)ws_size;

    hipMemsetAsync(d_out, 0, (size_t)out_size * sizeof(float), stream);

    init_kernel<<<(CAP + 255) / 256, 256, 0, stream>>>(counts, list_token, list_w, CAP);

    int n8 = T * D_DIM / 8;
    cvt_x_kernel<<<(n8 + 255) / 256, 256, 0, stream>>>(x, xb, n8);

    dim3 tb(32, 8);
    tconv_kernel<<<dim3(H_DIM / 32, D_DIM / 32, E_NUM), tb, 0, stream>>>(W1, w1t, D_DIM, H_DIM);
    tconv_kernel<<<dim3(H_DIM / 32, D_DIM / 32, E_NUM), tb, 0, stream>>>(W3, w3t, D_DIM, H_DIM);
    tconv_kernel<<<dim3(D_DIM / 32, H_DIM / 32, E_NUM), tb, 0, stream>>>(W2, w2t, H_DIM, D_DIM);

    gate_kernel<<<T / 4, 256, 0, stream>>>(x, gw, ridx, rw, counts, T);
    scan_kernel<<<1, 64, 0, stream>>>(counts, seg, fill);
    scatter_kernel<<<(npairs + 255) / 256, 256, 0, stream>>>(ridx, rw, fill, list_token, list_w, npairs);

    for (int c = 0; c < NCHUNK; ++c) {
        int cb = c * chunk_slots;
        gemm1_kernel<<<dim3(chunk_slots / BM, H_DIM / BN), 256, 0, stream>>>(
            xb, w1t, w3t, list_token, seg, hbuf, cb);
        gemm2_kernel<<<dim3(chunk_slots / BM, D_DIM / BN), 256, 0, stream>>>(
            hbuf, w2t, list_token, list_w, seg, out, cb);
    }
}

// Round 2
// 1259.755 us; speedup vs baseline: 1.9152x; 1.9152x over previous
//
#include <hip/hip_runtime.h>
#include <stdint.h>

#define D_DIM 512
#define H_DIM 2048
#define E_NUM 8
#define TOPK_N 2

typedef __attribute__((ext_vector_type(8))) short bf16x8;
typedef __attribute__((ext_vector_type(4))) float f32x4;

// async global->LDS, 16B per lane. LDS dst must be wave-uniform; HW adds lane*16.
#define GLOAD_LDS16(gsrc, ldst)                                                     \
    __builtin_amdgcn_global_load_lds(                                               \
        (const __attribute__((address_space(1))) void*)(gsrc),                      \
        (__attribute__((address_space(3))) void*)(ldst), 16, 0, 0)

static __device__ __forceinline__ unsigned short f2bf(float f) {
    unsigned u = __float_as_uint(f);
    unsigned r = (u + 0x7fffu + ((u >> 16) & 1u)) >> 16;
    return (unsigned short)r;
}

// ---------------- init: list=-1, zrow=0 ----------------
__global__ void init_kernel(int* list_token, float* list_w, unsigned short* zrow, int cap) {
    int id = blockIdx.x * blockDim.x + threadIdx.x;
    if (id < cap) { list_token[id] = -1; list_w[id] = 0.f; }
    if (id < D_DIM) zrow[id] = 0;
}

// ---------------- x fp32 -> bf16 ----------------
__global__ void cvt_x_kernel(const float* __restrict__ x, unsigned short* __restrict__ xb, int n8) {
    int id = blockIdx.x * blockDim.x + threadIdx.x;
    if (id >= n8) return;
    const float4* p = (const float4*)(x + (size_t)id * 8);
    float4 a = p[0], b = p[1];
    union { unsigned short s[8]; uint4 v; } o;
    o.s[0] = f2bf(a.x); o.s[1] = f2bf(a.y); o.s[2] = f2bf(a.z); o.s[3] = f2bf(a.w);
    o.s[4] = f2bf(b.x); o.s[5] = f2bf(b.y); o.s[6] = f2bf(b.z); o.s[7] = f2bf(b.w);
    *(uint4*)(xb + (size_t)id * 8) = o.v;
}

// ------------- transpose+convert: in fp32 [E][R][C] -> out bf16 [E][C][R] -------------
__global__ void tconv_kernel(const float* __restrict__ in, unsigned short* __restrict__ out,
                             int R, int C) {
    __shared__ float tile[32][33];
    int e = blockIdx.z;
    const float* src = in + (size_t)e * R * C;
    unsigned short* dst = out + (size_t)e * R * C;
    int c = blockIdx.x * 32 + threadIdx.x;
#pragma unroll
    for (int i = 0; i < 4; ++i) {
        int r = blockIdx.y * 32 + threadIdx.y + i * 8;
        tile[threadIdx.y + i * 8][threadIdx.x] = src[(size_t)r * C + c];
    }
    __syncthreads();
    int r2 = blockIdx.y * 32 + threadIdx.x;
#pragma unroll
    for (int i = 0; i < 4; ++i) {
        int c2 = blockIdx.x * 32 + threadIdx.y + i * 8;
        dst[(size_t)c2 * R + r2] = f2bf(tile[threadIdx.x][threadIdx.y + i * 8]);
    }
}

// ---------------- gating: fp32 logits, top-2 softmax (NO atomics) ----------------
__global__ void gate_kernel(const float* __restrict__ x, const float* __restrict__ gw,
                            int* __restrict__ ridx, float* __restrict__ rw, int T) {
    int wave = threadIdx.x >> 6;
    int lane = threadIdx.x & 63;
    int t = blockIdx.x * 4 + wave;
    if (t >= T) return;
    float acc[8] = {0.f, 0.f, 0.f, 0.f, 0.f, 0.f, 0.f, 0.f};
    const float* xr = x + (size_t)t * D_DIM;
#pragma unroll
    for (int i = 0; i < 8; ++i) {
        int d = lane + i * 64;
        float xv = xr[d];
        float4 g0 = *(const float4*)(gw + d * 8);
        float4 g1 = *(const float4*)(gw + d * 8 + 4);
        acc[0] += xv * g0.x; acc[1] += xv * g0.y; acc[2] += xv * g0.z; acc[3] += xv * g0.w;
        acc[4] += xv * g1.x; acc[5] += xv * g1.y; acc[6] += xv * g1.z; acc[7] += xv * g1.w;
    }
#pragma unroll
    for (int off = 32; off > 0; off >>= 1) {
#pragma unroll
        for (int e = 0; e < 8; ++e) acc[e] += __shfl_xor(acc[e], off, 64);
    }
    if (lane == 0) {
        int e0 = 0; float l0 = acc[0];
#pragma unroll
        for (int e = 1; e < 8; ++e) if (acc[e] > l0) { l0 = acc[e]; e0 = e; }
        int e1 = -1; float l1 = -1e30f;
#pragma unroll
        for (int e = 0; e < 8; ++e) if (e != e0 && acc[e] > l1) { l1 = acc[e]; e1 = e; }
        float w0 = 1.f / (1.f + expf(l1 - l0));
        ridx[t * 2] = e0; ridx[t * 2 + 1] = e1;
        rw[t * 2] = w0;  rw[t * 2 + 1] = 1.f - w0;
    }
}

// ---------------- per-block histogram (LDS atomics only) ----------------
__global__ void hist_kernel(const int* __restrict__ ridx, int* __restrict__ partial, int npairs) {
    __shared__ int cnt[E_NUM];
    if (threadIdx.x < E_NUM) cnt[threadIdx.x] = 0;
    __syncthreads();
    for (int i = blockIdx.x * blockDim.x + threadIdx.x; i < npairs; i += gridDim.x * blockDim.x)
        atomicAdd(&cnt[ridx[i]], 1);
    __syncthreads();
    if (threadIdx.x < E_NUM) partial[blockIdx.x * E_NUM + threadIdx.x] = cnt[threadIdx.x];
}

// ---------------- scan: padded seg offsets + per-block bases ----------------
__global__ void scan_kernel(const int* __restrict__ partial, int* __restrict__ seg,
                            int* __restrict__ block_base) {
    __shared__ int sp[64 * E_NUM];
    __shared__ int segl[E_NUM + 1];
    int tid = threadIdx.x;
    if (tid < 64 * E_NUM) sp[tid] = partial[tid];
    __syncthreads();
    if (tid == 0) {
        int off = 0;
        for (int e = 0; e < E_NUM; ++e) {
            segl[e] = off;
            int c = 0;
            for (int b = 0; b < 64; ++b) c += sp[b * E_NUM + e];
            off += (c + 127) & ~127;
        }
        segl[E_NUM] = off;
    }
    __syncthreads();
    if (tid < E_NUM) {
        int run = segl[tid];
        for (int b = 0; b < 64; ++b) { block_base[b * E_NUM + tid] = run; run += sp[b * E_NUM + tid]; }
        seg[tid] = segl[tid];
        if (tid == 0) seg[E_NUM] = segl[E_NUM];
    }
}

// ---------------- scatter: LDS counters + precomputed block base ----------------
__global__ void scatter_kernel(const int* __restrict__ ridx, const float* __restrict__ rw,
                               const int* __restrict__ block_base,
                               int* __restrict__ list_token, float* __restrict__ list_w, int npairs) {
    __shared__ int base[E_NUM];
    __shared__ int cnt[E_NUM];
    if (threadIdx.x < E_NUM) { base[threadIdx.x] = block_base[blockIdx.x * E_NUM + threadIdx.x]; cnt[threadIdx.x] = 0; }
    __syncthreads();
    for (int i = blockIdx.x * blockDim.x + threadIdx.x; i < npairs; i += gridDim.x * blockDim.x) {
        int e = ridx[i];
        int pos = base[e] + atomicAdd(&cnt[e], 1);
        list_token[pos] = i >> 1;
        list_w[pos] = rw[i];
    }
}

// ---------------- GEMM1: h = silu(X W1) * (X W3), 128x(64+64) tile, async staging ----------------
__global__ __launch_bounds__(256) void gemm1_kernel(
    const unsigned short* __restrict__ xb,
    const unsigned short* __restrict__ w1t,   // [E][H][D]
    const unsigned short* __restrict__ w3t,
    const unsigned short* __restrict__ zrow,
    const int* __restrict__ list_token,
    const int* __restrict__ seg,
    unsigned short* __restrict__ hbuf,        // [chunk_slots][H]
    int chunk_base) {
    __shared__ short As[128 * 64];            // rows: slots, XOR-swizzled chunks
    __shared__ short Bs[128 * 64];            // rows 0-63: W1 cols, 64-127: W3 cols

    int tid = threadIdx.x;
    int w = tid >> 6, l = tid & 63;
    int m0 = blockIdx.x * 128;
    int slot0 = chunk_base + m0;
    int n0 = blockIdx.y * 64;

    int e = 0;
#pragma unroll
    for (int i = 0; i < E_NUM - 1; ++i) if (slot0 >= seg[i + 1]) e = i + 1;
    const unsigned short* b1 = w1t + ((size_t)e * H_DIM + n0) * D_DIM;
    const unsigned short* b3 = w3t + ((size_t)e * H_DIM + n0) * D_DIM;

    int lr8 = l >> 3, p = l & 7;
    const unsigned short* aptr[4];
    const unsigned short* bptr[4];
#pragma unroll
    for (int q = 0; q < 4; ++q) {
        int row = (q * 4 + w) * 8 + lr8;       // 0..127
        int c = p ^ (row & 7);
        int tok = list_token[slot0 + row];
        aptr[q] = (tok >= 0 ? xb + (size_t)tok * D_DIM : zrow) + c * 8;
        bptr[q] = (row < 64 ? b1 + (size_t)row * D_DIM
                            : b3 + (size_t)(row - 64) * D_DIM) + c * 8;
    }

    int wm = (w & 1) * 64;
    int wn = (w >> 1) * 32;
    int lrr = l & 15;
    int lk = (l >> 4) * 8;

    f32x4 acc1[4][2] = {};
    f32x4 acc3[4][2] = {};

    for (int k0 = 0; k0 < D_DIM; k0 += 64) {
#pragma unroll
        for (int q = 0; q < 4; ++q) {
            GLOAD_LDS16(aptr[q] + k0, &As[(q * 4 + w) * 512]);
            GLOAD_LDS16(bptr[q] + k0, &Bs[(q * 4 + w) * 512]);
        }
        __syncthreads();
#pragma unroll
        for (int ks = 0; ks < 64; ks += 32) {
            int cblk = (ks + lk) >> 3;
            bf16x8 af[4], b1f[2], b3f[2];
#pragma unroll
            for (int i = 0; i < 4; ++i) {
                int row = wm + i * 16 + lrr;
                af[i] = *(const bf16x8*)&As[row * 64 + ((cblk ^ (row & 7)) << 3)];
            }
#pragma unroll
            for (int j = 0; j < 2; ++j) {
                int r1 = wn + j * 16 + lrr;
                b1f[j] = *(const bf16x8*)&Bs[r1 * 64 + ((cblk ^ (r1 & 7)) << 3)];
                int r3 = 64 + wn + j * 16 + lrr;
                b3f[j] = *(const bf16x8*)&Bs[r3 * 64 + ((cblk ^ (r3 & 7)) << 3)];
            }
#pragma unroll
            for (int i = 0; i < 4; ++i)
#pragma unroll
                for (int j = 0; j < 2; ++j) {
                    acc1[i][j] = __builtin_amdgcn_mfma_f32_16x16x32_bf16(af[i], b1f[j], acc1[i][j], 0, 0, 0);
                    acc3[i][j] = __builtin_amdgcn_mfma_f32_16x16x32_bf16(af[i], b3f[j], acc3[i][j], 0, 0, 0);
                }
        }
        __syncthreads();
    }

    int lrow0 = (l >> 4) * 4, lcol = l & 15;
#pragma unroll
    for (int i = 0; i < 4; ++i)
#pragma unroll
        for (int j = 0; j < 2; ++j)
#pragma unroll
            for (int r = 0; r < 4; ++r) {
                int row = wm + i * 16 + lrow0 + r;
                int col = wn + j * 16 + lcol;
                float v1 = acc1[i][j][r];
                float v3 = acc3[i][j][r];
                float h = v1 / (1.f + expf(-v1)) * v3;
                hbuf[(size_t)(m0 + row) * H_DIM + n0 + col] = f2bf(h);
            }
}

// ---------------- GEMM2: out[token] += w * (h W2), 128x64 tile ----------------
__global__ __launch_bounds__(256) void gemm2_kernel(
    const unsigned short* __restrict__ hbuf,
    const unsigned short* __restrict__ w2t,   // [E][D][H]
    const int* __restrict__ list_token,
    const float* __restrict__ list_w,
    const int* __restrict__ seg,
    float* __restrict__ out,
    int chunk_base) {
    __shared__ short As[128 * 64];
    __shared__ short Bs[64 * 64];
    __shared__ int ltok[128];
    __shared__ float lw[128];

    int tid = threadIdx.x;
    int w = tid >> 6, l = tid & 63;
    int m0 = blockIdx.x * 128;
    int slot0 = chunk_base + m0;
    int n0 = blockIdx.y * 64;

    if (tid < 128) { ltok[tid] = list_token[slot0 + tid]; lw[tid] = list_w[slot0 + tid]; }

    int e = 0;
#pragma unroll
    for (int i = 0; i < E_NUM - 1; ++i) if (slot0 >= seg[i + 1]) e = i + 1;
    const unsigned short* b2 = w2t + ((size_t)e * D_DIM + n0) * H_DIM;

    int lr8 = l >> 3, p = l & 7;
    const unsigned short* aptr[4];
    const unsigned short* bptr[2];
#pragma unroll
    for (int q = 0; q < 4; ++q) {
        int row = (q * 4 + w) * 8 + lr8;       // 0..127
        int c = p ^ (row & 7);
        aptr[q] = hbuf + (size_t)(m0 + row) * H_DIM + c * 8;
    }
#pragma unroll
    for (int q = 0; q < 2; ++q) {
        int row = (q * 4 + w) * 8 + lr8;       // 0..63
        int c = p ^ (row & 7);
        bptr[q] = b2 + (size_t)row * H_DIM + c * 8;
    }

    int wm = (w & 1) * 64;
    int wn = (w >> 1) * 32;
    int lrr = l & 15;
    int lk = (l >> 4) * 8;

    f32x4 acc[4][2] = {};

    for (int k0 = 0; k0 < H_DIM; k0 += 64) {
#pragma unroll
        for (int q = 0; q < 4; ++q) GLOAD_LDS16(aptr[q] + k0, &As[(q * 4 + w) * 512]);
#pragma unroll
        for (int q = 0; q < 2; ++q) GLOAD_LDS16(bptr[q] + k0, &Bs[(q * 4 + w) * 512]);
        __syncthreads();
#pragma unroll
        for (int ks = 0; ks < 64; ks += 32) {
            int cblk = (ks + lk) >> 3;
            bf16x8 af[4], bf[2];
#pragma unroll
            for (int i = 0; i < 4; ++i) {
                int row = wm + i * 16 + lrr;
                af[i] = *(const bf16x8*)&As[row * 64 + ((cblk ^ (row & 7)) << 3)];
            }
#pragma unroll
            for (int j = 0; j < 2; ++j) {
                int row = wn + j * 16 + lrr;
                bf[j] = *(const bf16x8*)&Bs[row * 64 + ((cblk ^ (row & 7)) << 3)];
            }
#pragma unroll
            for (int i = 0; i < 4; ++i)
#pragma unroll
                for (int j = 0; j < 2; ++j)
                    acc[i][j] = __builtin_amdgcn_mfma_f32_16x16x32_bf16(af[i], bf[j], acc[i][j], 0, 0, 0);
        }
        __syncthreads();
    }

    int lrow0 = (l >> 4) * 4, lcol = l & 15;
#pragma unroll
    for (int i = 0; i < 4; ++i)
#pragma unroll
        for (int j = 0; j < 2; ++j)
#pragma unroll
            for (int r = 0; r < 4; ++r) {
                int row = wm + i * 16 + lrow0 + r;
                int col = wn + j * 16 + lcol;
                int tok = ltok[row];
                if (tok >= 0)
                    atomicAdd(&out[(size_t)tok * D_DIM + n0 + col], acc[i][j][r] * lw[row]);
            }
}

extern "C" void kernel_launch(void* const* d_in, const int* in_sizes, int n_in,
                              void* d_out, int out_size, void* d_ws, size_t ws_size,
                              hipStream_t stream) {
    const float* x  = (const float*)d_in[0];
    const float* gw = (const float*)d_in[1];
    const float* W1 = (const float*)d_in[2];
    const float* W2 = (const float*)d_in[3];
    const float* W3 = (const float*)d_in[4];
    float* out = (float*)d_out;

    int T = in_sizes[0] / D_DIM;                 // 32768
    int npairs = T * TOPK_N;                     // 65536
    const int CAP = npairs + E_NUM * 128;        // 66560
    const int NCHUNK = 8;
    int chunk_slots = CAP / NCHUNK;              // 8320 = 65*128

    char* p = (char*)d_ws;
    size_t off = 0;
    auto take = [&](size_t bytes) {
        char* r = p + off;
        off = (off + bytes + 255) & ~(size_t)255;
        return r;
    };
    int* seg           = (int*)take((E_NUM + 1) * 4);
    int* partial       = (int*)take(64 * E_NUM * 4);
    int* block_base    = (int*)take(64 * E_NUM * 4);
    int* list_token    = (int*)take((size_t)CAP * 4);
    float* list_w      = (float*)take((size_t)CAP * 4);
    int* ridx          = (int*)take((size_t)npairs * 4);
    float* rw          = (float*)take((size_t)npairs * 4);
    unsigned short* zrow = (unsigned short*)take((size_t)D_DIM * 2);
    unsigned short* xb  = (unsigned short*)take((size_t)T * D_DIM * 2);
    unsigned short* w1t = (unsigned short*)take((size_t)E_NUM * D_DIM * H_DIM * 2);
    unsigned short* w3t = (unsigned short*)take((size_t)E_NUM * D_DIM * H_DIM * 2);
    unsigned short* w2t = (unsigned short*)take((size_t)E_NUM * D_DIM * H_DIM * 2);
    unsigned short* hbuf = (unsigned short*)take((size_t)chunk_slots * H_DIM * 2);
    (void)ws_size;

    hipMemsetAsync(d_out, 0, (size_t)out_size * sizeof(float), stream);

    init_kernel<<<(CAP + 255) / 256, 256, 0, stream>>>(list_token, list_w, zrow, CAP);

    int n8 = T * D_DIM / 8;
    cvt_x_kernel<<<(n8 + 255) / 256, 256, 0, stream>>>(x, xb, n8);

    dim3 tb(32, 8);
    tconv_kernel<<<dim3(H_DIM / 32, D_DIM / 32, E_NUM), tb, 0, stream>>>(W1, w1t, D_DIM, H_DIM);
    tconv_kernel<<<dim3(H_DIM / 32, D_DIM / 32, E_NUM), tb, 0, stream>>>(W3, w3t, D_DIM, H_DIM);
    tconv_kernel<<<dim3(D_DIM / 32, H_DIM / 32, E_NUM), tb, 0, stream>>>(W2, w2t, H_DIM, D_DIM);

    gate_kernel<<<T / 4, 256, 0, stream>>>(x, gw, ridx, rw, T);
    hist_kernel<<<64, 256, 0, stream>>>(ridx, partial, npairs);
    scan_kernel<<<1, 512, 0, stream>>>(partial, seg, block_base);
    scatter_kernel<<<64, 256, 0, stream>>>(ridx, rw, block_base, list_token, list_w, npairs);

    for (int c = 0; c < NCHUNK; ++c) {
        int cb = c * chunk_slots;
        gemm1_kernel<<<dim3(chunk_slots / 128, H_DIM / 64), 256, 0, stream>>>(
            xb, w1t, w3t, zrow, list_token, seg, hbuf, cb);
        gemm2_kernel<<<dim3(chunk_slots / 128, D_DIM / 64), 256, 0, stream>>>(
            hbuf, w2t, list_token, list_w, seg, out, cb);
    }
}

// Round 3
// 1045.196 us; speedup vs baseline: 2.3084x; 1.2053x over previous
//
#include <hip/hip_runtime.h>
#include <stdint.h>

#define D_DIM 512
#define H_DIM 2048
#define E_NUM 8
#define TOPK_N 2

typedef __attribute__((ext_vector_type(8))) short bf16x8;
typedef __attribute__((ext_vector_type(4))) float f32x4;

// async global->LDS, 16B per lane. LDS dst must be wave-uniform; HW adds lane*16.
#define GLOAD_LDS16(gsrc, ldst)                                                     \
    __builtin_amdgcn_global_load_lds(                                               \
        (const __attribute__((address_space(1))) void*)(gsrc),                      \
        (__attribute__((address_space(3))) void*)(ldst), 16, 0, 0)

static __device__ __forceinline__ unsigned short f2bf(float f) {
    unsigned u = __float_as_uint(f);
    unsigned r = (u + 0x7fffu + ((u >> 16) & 1u)) >> 16;
    return (unsigned short)r;
}

// ---------------- init: list=-1, zrow=0 ----------------
__global__ void init_kernel(int* list_token, float* list_w, unsigned short* zrow, int cap) {
    int id = blockIdx.x * blockDim.x + threadIdx.x;
    if (id < cap) { list_token[id] = -1; list_w[id] = 0.f; }
    if (id < D_DIM) zrow[id] = 0;
}

// -------- fused: x fp32 -> bf16 AND gate logits/top-2 (one pass over x) --------
// one wave per token; lane l owns d in [l*8, l*8+8)
__global__ void gate_cvt_kernel(const float* __restrict__ x, const float* __restrict__ gw,
                                unsigned short* __restrict__ xb,
                                int* __restrict__ ridx, float* __restrict__ rw, int T) {
    int wave = threadIdx.x >> 6;
    int lane = threadIdx.x & 63;
    int t = blockIdx.x * 4 + wave;
    if (t >= T) return;
    const float* xr = x + (size_t)t * D_DIM + lane * 8;
    float4 a = *(const float4*)xr;
    float4 b = *(const float4*)(xr + 4);
    // convert + store bf16
    union { unsigned short s[8]; uint4 v; } o;
    o.s[0] = f2bf(a.x); o.s[1] = f2bf(a.y); o.s[2] = f2bf(a.z); o.s[3] = f2bf(a.w);
    o.s[4] = f2bf(b.x); o.s[5] = f2bf(b.y); o.s[6] = f2bf(b.z); o.s[7] = f2bf(b.w);
    *(uint4*)(xb + (size_t)t * D_DIM + lane * 8) = o.v;
    // logits
    float xv[8] = {a.x, a.y, a.z, a.w, b.x, b.y, b.z, b.w};
    float acc[8] = {0.f, 0.f, 0.f, 0.f, 0.f, 0.f, 0.f, 0.f};
#pragma unroll
    for (int i = 0; i < 8; ++i) {
        int d = lane * 8 + i;
        float4 g0 = *(const float4*)(gw + d * 8);
        float4 g1 = *(const float4*)(gw + d * 8 + 4);
        acc[0] += xv[i] * g0.x; acc[1] += xv[i] * g0.y; acc[2] += xv[i] * g0.z; acc[3] += xv[i] * g0.w;
        acc[4] += xv[i] * g1.x; acc[5] += xv[i] * g1.y; acc[6] += xv[i] * g1.z; acc[7] += xv[i] * g1.w;
    }
#pragma unroll
    for (int off = 32; off > 0; off >>= 1) {
#pragma unroll
        for (int e = 0; e < 8; ++e) acc[e] += __shfl_xor(acc[e], off, 64);
    }
    if (lane == 0) {
        int e0 = 0; float l0 = acc[0];
#pragma unroll
        for (int e = 1; e < 8; ++e) if (acc[e] > l0) { l0 = acc[e]; e0 = e; }
        int e1 = -1; float l1 = -1e30f;
#pragma unroll
        for (int e = 0; e < 8; ++e) if (e != e0 && acc[e] > l1) { l1 = acc[e]; e1 = e; }
        float w0 = 1.f / (1.f + expf(l1 - l0));
        ridx[t * 2] = e0; ridx[t * 2 + 1] = e1;
        rw[t * 2] = w0;  rw[t * 2 + 1] = 1.f - w0;
    }
}

// ------------- transpose+convert: in fp32 [E][R][C] -> out bf16 [E][C][R] -------------
__global__ void tconv_kernel(const float* __restrict__ in, unsigned short* __restrict__ out,
                             int R, int C) {
    __shared__ float tile[32][33];
    int e = blockIdx.z;
    const float* src = in + (size_t)e * R * C;
    unsigned short* dst = out + (size_t)e * R * C;
    int c = blockIdx.x * 32 + threadIdx.x;
#pragma unroll
    for (int i = 0; i < 4; ++i) {
        int r = blockIdx.y * 32 + threadIdx.y + i * 8;
        tile[threadIdx.y + i * 8][threadIdx.x] = src[(size_t)r * C + c];
    }
    __syncthreads();
    int r2 = blockIdx.y * 32 + threadIdx.x;
#pragma unroll
    for (int i = 0; i < 4; ++i) {
        int c2 = blockIdx.x * 32 + threadIdx.y + i * 8;
        dst[(size_t)c2 * R + r2] = f2bf(tile[threadIdx.x][threadIdx.y + i * 8]);
    }
}

// ---------------- per-block histogram (LDS atomics only) ----------------
__global__ void hist_kernel(const int* __restrict__ ridx, int* __restrict__ partial, int npairs) {
    __shared__ int cnt[E_NUM];
    if (threadIdx.x < E_NUM) cnt[threadIdx.x] = 0;
    __syncthreads();
    for (int i = blockIdx.x * blockDim.x + threadIdx.x; i < npairs; i += gridDim.x * blockDim.x)
        atomicAdd(&cnt[ridx[i]], 1);
    __syncthreads();
    if (threadIdx.x < E_NUM) partial[blockIdx.x * E_NUM + threadIdx.x] = cnt[threadIdx.x];
}

// ---------------- scan: padded seg offsets + per-block bases ----------------
__global__ void scan_kernel(const int* __restrict__ partial, int* __restrict__ seg,
                            int* __restrict__ block_base) {
    __shared__ int sp[64 * E_NUM];
    __shared__ int segl[E_NUM + 1];
    int tid = threadIdx.x;
    if (tid < 64 * E_NUM) sp[tid] = partial[tid];
    __syncthreads();
    if (tid == 0) {
        int off = 0;
        for (int e = 0; e < E_NUM; ++e) {
            segl[e] = off;
            int c = 0;
            for (int b = 0; b < 64; ++b) c += sp[b * E_NUM + e];
            off += (c + 127) & ~127;
        }
        segl[E_NUM] = off;
    }
    __syncthreads();
    if (tid < E_NUM) {
        int run = segl[tid];
        for (int b = 0; b < 64; ++b) { block_base[b * E_NUM + tid] = run; run += sp[b * E_NUM + tid]; }
        seg[tid] = segl[tid];
        if (tid == 0) seg[E_NUM] = segl[E_NUM];
    }
}

// ---------------- scatter: LDS counters + precomputed block base ----------------
__global__ void scatter_kernel(const int* __restrict__ ridx, const float* __restrict__ rw,
                               const int* __restrict__ block_base,
                               int* __restrict__ list_token, float* __restrict__ list_w, int npairs) {
    __shared__ int base[E_NUM];
    __shared__ int cnt[E_NUM];
    if (threadIdx.x < E_NUM) { base[threadIdx.x] = block_base[blockIdx.x * E_NUM + threadIdx.x]; cnt[threadIdx.x] = 0; }
    __syncthreads();
    for (int i = blockIdx.x * blockDim.x + threadIdx.x; i < npairs; i += gridDim.x * blockDim.x) {
        int e = ridx[i];
        int pos = base[e] + atomicAdd(&cnt[e], 1);
        list_token[pos] = i >> 1;
        list_w[pos] = rw[i];
    }
}

// ---------------- GEMM1: h = silu(X W1) * (X W3), 128x(64+64) tile, async staging ----------------
// XCD-aware 1-D grid: b&7 = xcd slot (round-robin), per-XCD order m-inner/y-outer
// so the 9-tile A-slice (1.2 MB) stays L2-resident across the y sweep; B fetched once.
__global__ __launch_bounds__(256) void gemm1_kernel(
    const unsigned short* __restrict__ xb,
    const unsigned short* __restrict__ w1t,   // [E][H][D]
    const unsigned short* __restrict__ w3t,
    const unsigned short* __restrict__ zrow,
    const int* __restrict__ list_token,
    const int* __restrict__ seg,
    unsigned short* __restrict__ hbuf,        // [chunk_slots][H]
    int chunk_base, int MT, int MG) {
    __shared__ short As[128 * 64];
    __shared__ short Bs[128 * 64];

    int bfl = blockIdx.x;
    int xcd = bfl & 7;
    int idx = bfl >> 3;
    int mlocal = idx % MG;
    int yt = idx / MG;
    int mt = mlocal * 8 + xcd;
    if (mt >= MT) return;

    int tid = threadIdx.x;
    int w = tid >> 6, l = tid & 63;
    int m0 = mt * 128;
    int slot0 = chunk_base + m0;
    int n0 = yt * 64;

    int e = 0;
#pragma unroll
    for (int i = 0; i < E_NUM - 1; ++i) if (slot0 >= seg[i + 1]) e = i + 1;
    const unsigned short* b1 = w1t + ((size_t)e * H_DIM + n0) * D_DIM;
    const unsigned short* b3 = w3t + ((size_t)e * H_DIM + n0) * D_DIM;

    int lr8 = l >> 3, p = l & 7;
    const unsigned short* aptr[4];
    const unsigned short* bptr[4];
#pragma unroll
    for (int q = 0; q < 4; ++q) {
        int row = (q * 4 + w) * 8 + lr8;       // 0..127
        int c = p ^ (row & 7);
        int tok = list_token[slot0 + row];
        aptr[q] = (tok >= 0 ? xb + (size_t)tok * D_DIM : zrow) + c * 8;
        bptr[q] = (row < 64 ? b1 + (size_t)row * D_DIM
                            : b3 + (size_t)(row - 64) * D_DIM) + c * 8;
    }

    int wm = (w & 1) * 64;
    int wn = (w >> 1) * 32;
    int lrr = l & 15;
    int lk = (l >> 4) * 8;

    f32x4 acc1[4][2] = {};
    f32x4 acc3[4][2] = {};

    for (int k0 = 0; k0 < D_DIM; k0 += 64) {
#pragma unroll
        for (int q = 0; q < 4; ++q) {
            GLOAD_LDS16(aptr[q] + k0, &As[(q * 4 + w) * 512]);
            GLOAD_LDS16(bptr[q] + k0, &Bs[(q * 4 + w) * 512]);
        }
        __syncthreads();
#pragma unroll
        for (int ks = 0; ks < 64; ks += 32) {
            int cblk = (ks + lk) >> 3;
            bf16x8 af[4], b1f[2], b3f[2];
#pragma unroll
            for (int i = 0; i < 4; ++i) {
                int row = wm + i * 16 + lrr;
                af[i] = *(const bf16x8*)&As[row * 64 + ((cblk ^ (row & 7)) << 3)];
            }
#pragma unroll
            for (int j = 0; j < 2; ++j) {
                int r1 = wn + j * 16 + lrr;
                b1f[j] = *(const bf16x8*)&Bs[r1 * 64 + ((cblk ^ (r1 & 7)) << 3)];
                int r3 = 64 + wn + j * 16 + lrr;
                b3f[j] = *(const bf16x8*)&Bs[r3 * 64 + ((cblk ^ (r3 & 7)) << 3)];
            }
#pragma unroll
            for (int i = 0; i < 4; ++i)
#pragma unroll
                for (int j = 0; j < 2; ++j) {
                    acc1[i][j] = __builtin_amdgcn_mfma_f32_16x16x32_bf16(af[i], b1f[j], acc1[i][j], 0, 0, 0);
                    acc3[i][j] = __builtin_amdgcn_mfma_f32_16x16x32_bf16(af[i], b3f[j], acc3[i][j], 0, 0, 0);
                }
        }
        __syncthreads();
    }

    int lrow0 = (l >> 4) * 4, lcol = l & 15;
#pragma unroll
    for (int i = 0; i < 4; ++i)
#pragma unroll
        for (int j = 0; j < 2; ++j)
#pragma unroll
            for (int r = 0; r < 4; ++r) {
                int row = wm + i * 16 + lrow0 + r;
                int col = wn + j * 16 + lcol;
                float v1 = acc1[i][j][r];
                float v3 = acc3[i][j][r];
                float h = v1 / (1.f + expf(-v1)) * v3;
                hbuf[(size_t)(m0 + row) * H_DIM + n0 + col] = f2bf(h);
            }
}

// ---------------- GEMM2: out[token] += w * (h W2), 128x64 tile ----------------
// XCD-aware: per-XCD order y-inner/m-outer (W2 2.1 MB resident, A-tile hot per m)
__global__ __launch_bounds__(256) void gemm2_kernel(
    const unsigned short* __restrict__ hbuf,
    const unsigned short* __restrict__ w2t,   // [E][D][H]
    const int* __restrict__ list_token,
    const float* __restrict__ list_w,
    const int* __restrict__ seg,
    float* __restrict__ out,
    int chunk_base, int MT) {
    __shared__ short As[128 * 64];
    __shared__ short Bs[64 * 64];
    __shared__ int ltok[128];
    __shared__ float lw[128];

    int bfl = blockIdx.x;
    int xcd = bfl & 7;
    int idx = bfl >> 3;
    int yt = idx & 7;          // y-inner
    int mlocal = idx >> 3;
    int mt = mlocal * 8 + xcd;
    if (mt >= MT) return;

    int tid = threadIdx.x;
    int w = tid >> 6, l = tid & 63;
    int m0 = mt * 128;
    int slot0 = chunk_base + m0;
    int n0 = yt * 64;

    if (tid < 128) { ltok[tid] = list_token[slot0 + tid]; lw[tid] = list_w[slot0 + tid]; }

    int e = 0;
#pragma unroll
    for (int i = 0; i < E_NUM - 1; ++i) if (slot0 >= seg[i + 1]) e = i + 1;
    const unsigned short* b2 = w2t + ((size_t)e * D_DIM + n0) * H_DIM;

    int lr8 = l >> 3, p = l & 7;
    const unsigned short* aptr[4];
    const unsigned short* bptr[2];
#pragma unroll
    for (int q = 0; q < 4; ++q) {
        int row = (q * 4 + w) * 8 + lr8;       // 0..127
        int c = p ^ (row & 7);
        aptr[q] = hbuf + (size_t)(m0 + row) * H_DIM + c * 8;
    }
#pragma unroll
    for (int q = 0; q < 2; ++q) {
        int row = (q * 4 + w) * 8 + lr8;       // 0..63
        int c = p ^ (row & 7);
        bptr[q] = b2 + (size_t)row * H_DIM + c * 8;
    }

    int wm = (w & 1) * 64;
    int wn = (w >> 1) * 32;
    int lrr = l & 15;
    int lk = (l >> 4) * 8;

    f32x4 acc[4][2] = {};

    for (int k0 = 0; k0 < H_DIM; k0 += 64) {
#pragma unroll
        for (int q = 0; q < 4; ++q) GLOAD_LDS16(aptr[q] + k0, &As[(q * 4 + w) * 512]);
#pragma unroll
        for (int q = 0; q < 2; ++q) GLOAD_LDS16(bptr[q] + k0, &Bs[(q * 4 + w) * 512]);
        __syncthreads();
#pragma unroll
        for (int ks = 0; ks < 64; ks += 32) {
            int cblk = (ks + lk) >> 3;
            bf16x8 af[4], bf[2];
#pragma unroll
            for (int i = 0; i < 4; ++i) {
                int row = wm + i * 16 + lrr;
                af[i] = *(const bf16x8*)&As[row * 64 + ((cblk ^ (row & 7)) << 3)];
            }
#pragma unroll
            for (int j = 0; j < 2; ++j) {
                int row = wn + j * 16 + lrr;
                bf[j] = *(const bf16x8*)&Bs[row * 64 + ((cblk ^ (row & 7)) << 3)];
            }
#pragma unroll
            for (int i = 0; i < 4; ++i)
#pragma unroll
                for (int j = 0; j < 2; ++j)
                    acc[i][j] = __builtin_amdgcn_mfma_f32_16x16x32_bf16(af[i], bf[j], acc[i][j], 0, 0, 0);
        }
        __syncthreads();
    }

    int lrow0 = (l >> 4) * 4, lcol = l & 15;
#pragma unroll
    for (int i = 0; i < 4; ++i)
#pragma unroll
        for (int j = 0; j < 2; ++j)
#pragma unroll
            for (int r = 0; r < 4; ++r) {
                int row = wm + i * 16 + lrow0 + r;
                int col = wn + j * 16 + lcol;
                int tok = ltok[row];
                if (tok >= 0)
                    atomicAdd(&out[(size_t)tok * D_DIM + n0 + col], acc[i][j][r] * lw[row]);
            }
}

extern "C" void kernel_launch(void* const* d_in, const int* in_sizes, int n_in,
                              void* d_out, int out_size, void* d_ws, size_t ws_size,
                              hipStream_t stream) {
    const float* x  = (const float*)d_in[0];
    const float* gw = (const float*)d_in[1];
    const float* W1 = (const float*)d_in[2];
    const float* W2 = (const float*)d_in[3];
    const float* W3 = (const float*)d_in[4];
    float* out = (float*)d_out;

    int T = in_sizes[0] / D_DIM;                 // 32768
    int npairs = T * TOPK_N;                     // 65536
    const int CAP = npairs + E_NUM * 128;        // 66560
    const int NCHUNK = 8;
    int chunk_slots = CAP / NCHUNK;              // 8320 = 65*128
    int MT = chunk_slots / 128;                  // 65 m-tiles per chunk
    int MG = (MT + 7) / 8;                       // 9 m-tiles per XCD slot

    char* p = (char*)d_ws;
    size_t off = 0;
    auto take = [&](size_t bytes) {
        char* r = p + off;
        off = (off + bytes + 255) & ~(size_t)255;
        return r;
    };
    int* seg           = (int*)take((E_NUM + 1) * 4);
    int* partial       = (int*)take(64 * E_NUM * 4);
    int* block_base    = (int*)take(64 * E_NUM * 4);
    int* list_token    = (int*)take((size_t)CAP * 4);
    float* list_w      = (float*)take((size_t)CAP * 4);
    int* ridx          = (int*)take((size_t)npairs * 4);
    float* rw          = (float*)take((size_t)npairs * 4);
    unsigned short* zrow = (unsigned short*)take((size_t)D_DIM * 2);
    unsigned short* xb  = (unsigned short*)take((size_t)T * D_DIM * 2);
    unsigned short* w1t = (unsigned short*)take((size_t)E_NUM * D_DIM * H_DIM * 2);
    unsigned short* w3t = (unsigned short*)take((size_t)E_NUM * D_DIM * H_DIM * 2);
    unsigned short* w2t = (unsigned short*)take((size_t)E_NUM * D_DIM * H_DIM * 2);
    unsigned short* hbuf = (unsigned short*)take((size_t)chunk_slots * H_DIM * 2);
    (void)ws_size;

    hipMemsetAsync(d_out, 0, (size_t)out_size * sizeof(float), stream);

    init_kernel<<<(CAP + 255) / 256, 256, 0, stream>>>(list_token, list_w, zrow, CAP);

    gate_cvt_kernel<<<T / 4, 256, 0, stream>>>(x, gw, xb, ridx, rw, T);

    dim3 tb(32, 8);
    tconv_kernel<<<dim3(H_DIM / 32, D_DIM / 32, E_NUM), tb, 0, stream>>>(W1, w1t, D_DIM, H_DIM);
    tconv_kernel<<<dim3(H_DIM / 32, D_DIM / 32, E_NUM), tb, 0, stream>>>(W3, w3t, D_DIM, H_DIM);
    tconv_kernel<<<dim3(D_DIM / 32, H_DIM / 32, E_NUM), tb, 0, stream>>>(W2, w2t, H_DIM, D_DIM);

    hist_kernel<<<64, 256, 0, stream>>>(ridx, partial, npairs);
    scan_kernel<<<1, 512, 0, stream>>>(partial, seg, block_base);
    scatter_kernel<<<64, 256, 0, stream>>>(ridx, rw, block_base, list_token, list_w, npairs);

    int g1_grid = 8 * MG * (H_DIM / 64);         // 8 xcd slots * 9 m * 32 y = 2304
    int g2_grid = 8 * (D_DIM / 64) * MG;         // 8 xcd slots * 8 y * 9 m = 576
    for (int c = 0; c < NCHUNK; ++c) {
        int cb = c * chunk_slots;
        gemm1_kernel<<<g1_grid, 256, 0, stream>>>(
            xb, w1t, w3t, zrow, list_token, seg, hbuf, cb, MT, MG);
        gemm2_kernel<<<g2_grid, 256, 0, stream>>>(
            hbuf, w2t, list_token, list_w, seg, out, cb, MT);
    }
}

// Round 4
// 1031.886 us; speedup vs baseline: 2.3381x; 1.0129x over previous
//
#include <hip/hip_runtime.h>
#include <stdint.h>

#define D_DIM 512
#define H_DIM 2048
#define E_NUM 8
#define TOPK_N 2

typedef __attribute__((ext_vector_type(8))) short bf16x8;
typedef __attribute__((ext_vector_type(4))) float f32x4;

// async global->LDS, 16B per lane. LDS dst must be wave-uniform; HW adds lane*16.
#define GLOAD_LDS16(gsrc, ldst)                                                     \
    __builtin_amdgcn_global_load_lds(                                               \
        (const __attribute__((address_space(1))) void*)(gsrc),                      \
        (__attribute__((address_space(3))) void*)(ldst), 16, 0, 0)

static __device__ __forceinline__ unsigned short f2bf(float f) {
    unsigned u = __float_as_uint(f);
    unsigned r = (u + 0x7fffu + ((u >> 16) & 1u)) >> 16;
    return (unsigned short)r;
}

// ---------------- init: list=-1, zrow=0 ----------------
__global__ void init_kernel(int* list_token, float* list_w, unsigned short* zrow, int cap) {
    int id = blockIdx.x * blockDim.x + threadIdx.x;
    if (id < cap) { list_token[id] = -1; list_w[id] = 0.f; }
    if (id < D_DIM) zrow[id] = 0;
}

// ---------------- gw [D][E] -> gwT [E][D] (tiny) ----------------
__global__ void gwt_kernel(const float* __restrict__ gw, float* __restrict__ gwT) {
    int id = blockIdx.x * blockDim.x + threadIdx.x;   // 4096
    int e = id >> 9, d = id & 511;
    gwT[id] = gw[d * E_NUM + e];
}

// -------- fused: x fp32 -> bf16 AND gate logits/top-2 (one pass over x) --------
// one wave per token; lane l owns d in [l*8, l*8+8). gwT reads are coalesced.
__global__ void gate_cvt_kernel(const float* __restrict__ x, const float* __restrict__ gwT,
                                unsigned short* __restrict__ xb,
                                int* __restrict__ ridx, float* __restrict__ rw, int T) {
    int wave = threadIdx.x >> 6;
    int lane = threadIdx.x & 63;
    int t = blockIdx.x * 4 + wave;
    if (t >= T) return;
    const float* xr = x + (size_t)t * D_DIM + lane * 8;
    float4 a = *(const float4*)xr;
    float4 b = *(const float4*)(xr + 4);
    union { unsigned short s[8]; uint4 v; } o;
    o.s[0] = f2bf(a.x); o.s[1] = f2bf(a.y); o.s[2] = f2bf(a.z); o.s[3] = f2bf(a.w);
    o.s[4] = f2bf(b.x); o.s[5] = f2bf(b.y); o.s[6] = f2bf(b.z); o.s[7] = f2bf(b.w);
    *(uint4*)(xb + (size_t)t * D_DIM + lane * 8) = o.v;
    float acc[8];
#pragma unroll
    for (int e = 0; e < 8; ++e) {
        const float* g = gwT + e * D_DIM + lane * 8;
        float4 g0 = *(const float4*)g;
        float4 g1 = *(const float4*)(g + 4);
        acc[e] = a.x * g0.x + a.y * g0.y + a.z * g0.z + a.w * g0.w
               + b.x * g1.x + b.y * g1.y + b.z * g1.z + b.w * g1.w;
    }
#pragma unroll
    for (int off = 32; off > 0; off >>= 1) {
#pragma unroll
        for (int e = 0; e < 8; ++e) acc[e] += __shfl_xor(acc[e], off, 64);
    }
    if (lane == 0) {
        int e0 = 0; float l0 = acc[0];
#pragma unroll
        for (int e = 1; e < 8; ++e) if (acc[e] > l0) { l0 = acc[e]; e0 = e; }
        int e1 = -1; float l1 = -1e30f;
#pragma unroll
        for (int e = 0; e < 8; ++e) if (e != e0 && acc[e] > l1) { l1 = acc[e]; e1 = e; }
        float w0 = 1.f / (1.f + expf(l1 - l0));
        ridx[t * 2] = e0; ridx[t * 2 + 1] = e1;
        rw[t * 2] = w0;  rw[t * 2 + 1] = 1.f - w0;
    }
}

// ------------- transpose+convert: in fp32 [E][R][C] -> out bf16 [E][C][R] -------------
__global__ void tconv_kernel(const float* __restrict__ in, unsigned short* __restrict__ out,
                             int R, int C) {
    __shared__ float tile[32][33];
    int e = blockIdx.z;
    const float* src = in + (size_t)e * R * C;
    unsigned short* dst = out + (size_t)e * R * C;
    int c = blockIdx.x * 32 + threadIdx.x;
#pragma unroll
    for (int i = 0; i < 4; ++i) {
        int r = blockIdx.y * 32 + threadIdx.y + i * 8;
        tile[threadIdx.y + i * 8][threadIdx.x] = src[(size_t)r * C + c];
    }
    __syncthreads();
    int r2 = blockIdx.y * 32 + threadIdx.x;
#pragma unroll
    for (int i = 0; i < 4; ++i) {
        int c2 = blockIdx.x * 32 + threadIdx.y + i * 8;
        dst[(size_t)c2 * R + r2] = f2bf(tile[threadIdx.x][threadIdx.y + i * 8]);
    }
}

// ---------------- per-block histogram (LDS atomics only) ----------------
__global__ void hist_kernel(const int* __restrict__ ridx, int* __restrict__ partial, int npairs) {
    __shared__ int cnt[E_NUM];
    if (threadIdx.x < E_NUM) cnt[threadIdx.x] = 0;
    __syncthreads();
    for (int i = blockIdx.x * blockDim.x + threadIdx.x; i < npairs; i += gridDim.x * blockDim.x)
        atomicAdd(&cnt[ridx[i]], 1);
    __syncthreads();
    if (threadIdx.x < E_NUM) partial[blockIdx.x * E_NUM + threadIdx.x] = cnt[threadIdx.x];
}

// ---------------- scan: padded seg offsets + per-block bases ----------------
__global__ void scan_kernel(const int* __restrict__ partial, int* __restrict__ seg,
                            int* __restrict__ block_base) {
    __shared__ int sp[64 * E_NUM];
    __shared__ int segl[E_NUM + 1];
    int tid = threadIdx.x;
    if (tid < 64 * E_NUM) sp[tid] = partial[tid];
    __syncthreads();
    if (tid == 0) {
        int off = 0;
        for (int e = 0; e < E_NUM; ++e) {
            segl[e] = off;
            int c = 0;
            for (int b = 0; b < 64; ++b) c += sp[b * E_NUM + e];
            off += (c + 127) & ~127;
        }
        segl[E_NUM] = off;
    }
    __syncthreads();
    if (tid < E_NUM) {
        int run = segl[tid];
        for (int b = 0; b < 64; ++b) { block_base[b * E_NUM + tid] = run; run += sp[b * E_NUM + tid]; }
        seg[tid] = segl[tid];
        if (tid == 0) seg[E_NUM] = segl[E_NUM];
    }
}

// ---------------- scatter: LDS counters + precomputed block base ----------------
__global__ void scatter_kernel(const int* __restrict__ ridx, const float* __restrict__ rw,
                               const int* __restrict__ block_base,
                               int* __restrict__ list_token, float* __restrict__ list_w, int npairs) {
    __shared__ int base[E_NUM];
    __shared__ int cnt[E_NUM];
    if (threadIdx.x < E_NUM) { base[threadIdx.x] = block_base[blockIdx.x * E_NUM + threadIdx.x]; cnt[threadIdx.x] = 0; }
    __syncthreads();
    for (int i = blockIdx.x * blockDim.x + threadIdx.x; i < npairs; i += gridDim.x * blockDim.x) {
        int e = ridx[i];
        int pos = base[e] + atomicAdd(&cnt[e], 1);
        list_token[pos] = i >> 1;
        list_w[pos] = rw[i];
    }
}

// ---------------- GEMM1: h = silu(X W1) * (X W3), 128x(64+64) tile, async staging ----------------
// XCD-aware 1-D grid: b&7 = xcd slot, per-XCD order m-inner/y-outer (A-slice L2-resident).
__global__ __launch_bounds__(256) void gemm1_kernel(
    const unsigned short* __restrict__ xb,
    const unsigned short* __restrict__ w1t,   // [E][H][D]
    const unsigned short* __restrict__ w3t,
    const unsigned short* __restrict__ zrow,
    const int* __restrict__ list_token,
    const int* __restrict__ seg,
    unsigned short* __restrict__ hbuf,        // [chunk_slots][H]
    int chunk_base, int MT, int MG) {
    __shared__ short As[128 * 64];
    __shared__ short Bs[128 * 64];

    int bfl = blockIdx.x;
    int xcd = bfl & 7;
    int idx = bfl >> 3;
    int mlocal = idx % MG;
    int yt = idx / MG;
    int mt = mlocal * 8 + xcd;
    if (mt >= MT) return;

    int tid = threadIdx.x;
    int w = tid >> 6, l = tid & 63;
    int m0 = mt * 128;
    int slot0 = chunk_base + m0;
    int n0 = yt * 64;

    int e = 0;
#pragma unroll
    for (int i = 0; i < E_NUM - 1; ++i) if (slot0 >= seg[i + 1]) e = i + 1;
    const unsigned short* b1 = w1t + ((size_t)e * H_DIM + n0) * D_DIM;
    const unsigned short* b3 = w3t + ((size_t)e * H_DIM + n0) * D_DIM;

    int lr8 = l >> 3, p = l & 7;
    const unsigned short* aptr[4];
    const unsigned short* bptr[4];
#pragma unroll
    for (int q = 0; q < 4; ++q) {
        int row = (q * 4 + w) * 8 + lr8;       // 0..127
        int c = p ^ (row & 7);
        int tok = list_token[slot0 + row];
        aptr[q] = (tok >= 0 ? xb + (size_t)tok * D_DIM : zrow) + c * 8;
        bptr[q] = (row < 64 ? b1 + (size_t)row * D_DIM
                            : b3 + (size_t)(row - 64) * D_DIM) + c * 8;
    }

    int wm = (w & 1) * 64;
    int wn = (w >> 1) * 32;
    int lrr = l & 15;
    int lk = (l >> 4) * 8;

    f32x4 acc1[4][2] = {};
    f32x4 acc3[4][2] = {};

    for (int k0 = 0; k0 < D_DIM; k0 += 64) {
#pragma unroll
        for (int q = 0; q < 4; ++q) {
            GLOAD_LDS16(aptr[q] + k0, &As[(q * 4 + w) * 512]);
            GLOAD_LDS16(bptr[q] + k0, &Bs[(q * 4 + w) * 512]);
        }
        __syncthreads();
#pragma unroll
        for (int ks = 0; ks < 64; ks += 32) {
            int cblk = (ks + lk) >> 3;
            bf16x8 af[4], b1f[2], b3f[2];
#pragma unroll
            for (int i = 0; i < 4; ++i) {
                int row = wm + i * 16 + lrr;
                af[i] = *(const bf16x8*)&As[row * 64 + ((cblk ^ (row & 7)) << 3)];
            }
#pragma unroll
            for (int j = 0; j < 2; ++j) {
                int r1 = wn + j * 16 + lrr;
                b1f[j] = *(const bf16x8*)&Bs[r1 * 64 + ((cblk ^ (r1 & 7)) << 3)];
                int r3 = 64 + wn + j * 16 + lrr;
                b3f[j] = *(const bf16x8*)&Bs[r3 * 64 + ((cblk ^ (r3 & 7)) << 3)];
            }
#pragma unroll
            for (int i = 0; i < 4; ++i)
#pragma unroll
                for (int j = 0; j < 2; ++j) {
                    acc1[i][j] = __builtin_amdgcn_mfma_f32_16x16x32_bf16(af[i], b1f[j], acc1[i][j], 0, 0, 0);
                    acc3[i][j] = __builtin_amdgcn_mfma_f32_16x16x32_bf16(af[i], b3f[j], acc3[i][j], 0, 0, 0);
                }
        }
        __syncthreads();
    }

    int lrow0 = (l >> 4) * 4, lcol = l & 15;
#pragma unroll
    for (int i = 0; i < 4; ++i)
#pragma unroll
        for (int j = 0; j < 2; ++j)
#pragma unroll
            for (int r = 0; r < 4; ++r) {
                int row = wm + i * 16 + lrow0 + r;
                int col = wn + j * 16 + lcol;
                float v1 = acc1[i][j][r];
                float v3 = acc3[i][j][r];
                float h = v1 / (1.f + expf(-v1)) * v3;
                hbuf[(size_t)(m0 + row) * H_DIM + n0 + col] = f2bf(h);
            }
}

// ---------------- GEMM2: out[token] += w * (h W2), 128x128 tile, K=2048 ----------------
// XCD-aware: y-inner (4 ys), m-outer per XCD.
__global__ __launch_bounds__(256) void gemm2_kernel(
    const unsigned short* __restrict__ hbuf,
    const unsigned short* __restrict__ w2t,   // [E][D][H]
    const int* __restrict__ list_token,
    const float* __restrict__ list_w,
    const int* __restrict__ seg,
    float* __restrict__ out,
    int chunk_base, int MT) {
    __shared__ short As[128 * 64];
    __shared__ short Bs[128 * 64];
    __shared__ int ltok[128];
    __shared__ float lw[128];

    int bfl = blockIdx.x;
    int xcd = bfl & 7;
    int idx = bfl >> 3;
    int yt = idx & 3;          // y-inner (D/128 = 4)
    int mlocal = idx >> 2;
    int mt = mlocal * 8 + xcd;
    if (mt >= MT) return;

    int tid = threadIdx.x;
    int w = tid >> 6, l = tid & 63;
    int m0 = mt * 128;
    int slot0 = chunk_base + m0;
    int n0 = yt * 128;

    if (tid < 128) { ltok[tid] = list_token[slot0 + tid]; lw[tid] = list_w[slot0 + tid]; }

    int e = 0;
#pragma unroll
    for (int i = 0; i < E_NUM - 1; ++i) if (slot0 >= seg[i + 1]) e = i + 1;
    const unsigned short* b2 = w2t + ((size_t)e * D_DIM + n0) * H_DIM;

    int lr8 = l >> 3, p = l & 7;
    const unsigned short* aptr[4];
    const unsigned short* bptr[4];
#pragma unroll
    for (int q = 0; q < 4; ++q) {
        int row = (q * 4 + w) * 8 + lr8;       // 0..127
        int c = p ^ (row & 7);
        aptr[q] = hbuf + (size_t)(m0 + row) * H_DIM + c * 8;
        bptr[q] = b2 + (size_t)row * H_DIM + c * 8;
    }

    int wm = (w & 1) * 64;
    int wn = (w >> 1) * 64;
    int lrr = l & 15;
    int lk = (l >> 4) * 8;

    f32x4 acc[4][4] = {};

    for (int k0 = 0; k0 < H_DIM; k0 += 64) {
#pragma unroll
        for (int q = 0; q < 4; ++q) {
            GLOAD_LDS16(aptr[q] + k0, &As[(q * 4 + w) * 512]);
            GLOAD_LDS16(bptr[q] + k0, &Bs[(q * 4 + w) * 512]);
        }
        __syncthreads();
#pragma unroll
        for (int ks = 0; ks < 64; ks += 32) {
            int cblk = (ks + lk) >> 3;
            bf16x8 af[4], bf[4];
#pragma unroll
            for (int i = 0; i < 4; ++i) {
                int row = wm + i * 16 + lrr;
                af[i] = *(const bf16x8*)&As[row * 64 + ((cblk ^ (row & 7)) << 3)];
            }
#pragma unroll
            for (int j = 0; j < 4; ++j) {
                int row = wn + j * 16 + lrr;
                bf[j] = *(const bf16x8*)&Bs[row * 64 + ((cblk ^ (row & 7)) << 3)];
            }
#pragma unroll
            for (int i = 0; i < 4; ++i)
#pragma unroll
                for (int j = 0; j < 4; ++j)
                    acc[i][j] = __builtin_amdgcn_mfma_f32_16x16x32_bf16(af[i], bf[j], acc[i][j], 0, 0, 0);
        }
        __syncthreads();
    }

    int lrow0 = (l >> 4) * 4, lcol = l & 15;
#pragma unroll
    for (int i = 0; i < 4; ++i)
#pragma unroll
        for (int j = 0; j < 4; ++j)
#pragma unroll
            for (int r = 0; r < 4; ++r) {
                int row = wm + i * 16 + lrow0 + r;
                int col = wn + j * 16 + lcol;
                int tok = ltok[row];
                if (tok >= 0)
                    atomicAdd(&out[(size_t)tok * D_DIM + n0 + col], acc[i][j][r] * lw[row]);
            }
}

extern "C" void kernel_launch(void* const* d_in, const int* in_sizes, int n_in,
                              void* d_out, int out_size, void* d_ws, size_t ws_size,
                              hipStream_t stream) {
    const float* x  = (const float*)d_in[0];
    const float* gw = (const float*)d_in[1];
    const float* W1 = (const float*)d_in[2];
    const float* W2 = (const float*)d_in[3];
    const float* W3 = (const float*)d_in[4];
    float* out = (float*)d_out;

    int T = in_sizes[0] / D_DIM;                 // 32768
    int npairs = T * TOPK_N;                     // 65536
    const int CAP = npairs + E_NUM * 128;        // 66560 = 520*128
    const int NCHUNK = 4;
    int chunk_slots = CAP / NCHUNK;              // 16640 = 130*128
    int MT = chunk_slots / 128;                  // 130 m-tiles per chunk
    int MG = (MT + 7) / 8;                       // 17 m-tiles per XCD slot

    char* p = (char*)d_ws;
    size_t off = 0;
    auto take = [&](size_t bytes) {
        char* r = p + off;
        off = (off + bytes + 255) & ~(size_t)255;
        return r;
    };
    int* seg           = (int*)take((E_NUM + 1) * 4);
    int* partial       = (int*)take(64 * E_NUM * 4);
    int* block_base    = (int*)take(64 * E_NUM * 4);
    int* list_token    = (int*)take((size_t)CAP * 4);
    float* list_w      = (float*)take((size_t)CAP * 4);
    int* ridx          = (int*)take((size_t)npairs * 4);
    float* rw          = (float*)take((size_t)npairs * 4);
    float* gwT         = (float*)take((size_t)E_NUM * D_DIM * 4);
    unsigned short* zrow = (unsigned short*)take((size_t)D_DIM * 2);
    unsigned short* xb  = (unsigned short*)take((size_t)T * D_DIM * 2);
    unsigned short* w1t = (unsigned short*)take((size_t)E_NUM * D_DIM * H_DIM * 2);
    unsigned short* w3t = (unsigned short*)take((size_t)E_NUM * D_DIM * H_DIM * 2);
    unsigned short* w2t = (unsigned short*)take((size_t)E_NUM * D_DIM * H_DIM * 2);
    unsigned short* hbuf = (unsigned short*)take((size_t)chunk_slots * H_DIM * 2);
    (void)ws_size;

    hipMemsetAsync(d_out, 0, (size_t)out_size * sizeof(float), stream);

    init_kernel<<<(CAP + 255) / 256, 256, 0, stream>>>(list_token, list_w, zrow, CAP);
    gwt_kernel<<<(E_NUM * D_DIM) / 256, 256, 0, stream>>>(gw, gwT);

    gate_cvt_kernel<<<T / 4, 256, 0, stream>>>(x, gwT, xb, ridx, rw, T);

    dim3 tb(32, 8);
    tconv_kernel<<<dim3(H_DIM / 32, D_DIM / 32, E_NUM), tb, 0, stream>>>(W1, w1t, D_DIM, H_DIM);
    tconv_kernel<<<dim3(H_DIM / 32, D_DIM / 32, E_NUM), tb, 0, stream>>>(W3, w3t, D_DIM, H_DIM);
    tconv_kernel<<<dim3(D_DIM / 32, H_DIM / 32, E_NUM), tb, 0, stream>>>(W2, w2t, H_DIM, D_DIM);

    hist_kernel<<<64, 256, 0, stream>>>(ridx, partial, npairs);
    scan_kernel<<<1, 512, 0, stream>>>(partial, seg, block_base);
    scatter_kernel<<<64, 256, 0, stream>>>(ridx, rw, block_base, list_token, list_w, npairs);

    int g1_grid = 8 * MG * (H_DIM / 64);         // 8 * 17 * 32 = 4352
    int g2_grid = 8 * MG * (D_DIM / 128);        // 8 * 17 * 4  = 544
    for (int c = 0; c < NCHUNK; ++c) {
        int cb = c * chunk_slots;
        gemm1_kernel<<<g1_grid, 256, 0, stream>>>(
            xb, w1t, w3t, zrow, list_token, seg, hbuf, cb, MT, MG);
        gemm2_kernel<<<g2_grid, 256, 0, stream>>>(
            hbuf, w2t, list_token, list_w, seg, out, cb, MT);
    }
}